// Round 7
// baseline (158.114 us; speedup 1.0000x reference)
//
#include <hip/hip_runtime.h>
#include <cstdint>

#define HB 8
#define CM 128
#define NHEAD 8
#define NPT 8
#define DHD 16
#define HS 64
#define WS 64
#define LTOT 4096
#define NQA 192   // fused off(128) + attn(64)

typedef float floatx4 __attribute__((ext_vector_type(4)));
typedef short bf16x8 __attribute__((ext_vector_type(8)));

__device__ __forceinline__ unsigned short f2bf_rne(float x) {
  unsigned u = __float_as_uint(x);
  return (unsigned short)((u + 0x7FFFu + ((u >> 16) & 1)) >> 16);
}
// truncation split: x ~= hi + lo
__device__ __forceinline__ void split_bf(float x, unsigned short& h, unsigned short& l) {
  unsigned u = __float_as_uint(x);
  h = (unsigned short)(u >> 16);
  float r = x - __uint_as_float(u & 0xFFFF0000u);
  l = (unsigned short)(__float_as_uint(r) >> 16);
}
__device__ __forceinline__ float fast_tanh(float x) {
  float e = __expf(2.0f * x);
  return 1.0f - 2.0f / (e + 1.0f);
}

// Weight prep: bf16 hi/lo fragment layout, element (n,k) at (k>>3)*Nn*8 + n*8 + (k&7).
__global__ __launch_bounds__(256) void prep(const float* __restrict__ Wv,
                                            const float* __restrict__ Wo,
                                            const float* __restrict__ Wa,
                                            const float* __restrict__ Ww,
                                            const float* __restrict__ bo,
                                            const float* __restrict__ ba,
                                            unsigned short* __restrict__ wf_val,
                                            unsigned short* __restrict__ wf_qa,
                                            unsigned short* __restrict__ wf_out,
                                            float* __restrict__ bias_qa) {
  const int gid = blockIdx.x * 256 + threadIdx.x;  // 14336 = 32 k4 * 448 n
  const int k4 = gid / 448;
  const int ng = gid - k4 * 448;

  const float* src;
  unsigned short* dst;
  int Nsrc, Nn, nd, n;
  if (ng < 128) {        src = Wv; dst = wf_val; Nsrc = 128; Nn = 128; n = ng;        nd = n; }
  else if (ng < 256) {   src = Wo; dst = wf_qa;  Nsrc = 128; Nn = 192; n = ng - 128;  nd = n; }
  else if (ng < 320) {   src = Wa; dst = wf_qa;  Nsrc = 64;  Nn = 192; n = ng - 256;  nd = n + 128; }
  else {                 src = Ww; dst = wf_out; Nsrc = 128; Nn = 128; n = ng - 320;  nd = n; }

  ushort4 hi, lo;
  split_bf(src[(k4 * 4 + 0) * Nsrc + n], hi.x, lo.x);
  split_bf(src[(k4 * 4 + 1) * Nsrc + n], hi.y, lo.y);
  split_bf(src[(k4 * 4 + 2) * Nsrc + n], hi.z, lo.z);
  split_bf(src[(k4 * 4 + 3) * Nsrc + n], hi.w, lo.w);
  const int off = (k4 >> 1) * Nn * 8 + nd * 8 + (k4 & 1) * 4;
  *(ushort4*)(dst + off) = hi;
  *(ushort4*)(dst + Nn * 128 + off) = lo;

  if (gid < 128) bias_qa[gid] = bo[gid];
  else if (gid < 192) bias_qa[gid] = ba[gid - 128];
}

// Full-width MFMA GEMM body: tile 64 m x N n per block, A staged ONCE.
// 4 waves; wave tile = 32 m x N/2 n. 3-term bf16 split, K=128.
// OUT 0: value layout; OUT 1: row-major [b][l][NQA].
template <int N, int OUT_MODE>
__device__ __forceinline__ void gemm_wide(const float* __restrict__ A,
                                          const unsigned short* __restrict__ WF,
                                          const float* __restrict__ bias,
                                          float* __restrict__ out,
                                          int b, int ml0, int t, char* smem) {
  constexpr int NT = N / 32;                   // 16-wide n-tiles per wave
  unsigned short* AB = (unsigned short*)smem;  // hi [64][128]; lo at +8192

  // stage A (fp32 k-major [b][128][LTOT]) -> bf16 hi/lo, swizzled
  {
    const float* src = A + (size_t)b * CM * LTOT + ml0;
    const int x = t & 63, kq = t >> 6;
#pragma unroll
    for (int i = 0; i < 8; i++) {
      const int kb = kq * 4 + i * 16;
      ushort4 hi, lo;
      split_bf(src[(size_t)(kb + 0) * LTOT + x], hi.x, lo.x);
      split_bf(src[(size_t)(kb + 1) * LTOT + x], hi.y, lo.y);
      split_bf(src[(size_t)(kb + 2) * LTOT + x], hi.z, lo.z);
      split_bf(src[(size_t)(kb + 3) * LTOT + x], hi.w, lo.w);
      const int off = x * 128 + (((kb >> 3) ^ (x & 15)) << 3) + (kb & 7);
      *(ushort4*)(AB + off) = hi;
      *(ushort4*)(AB + 8192 + off) = lo;
    }
  }
  __syncthreads();

  const int w = t >> 6, lane = t & 63;
  const int wm = (w >> 1) * 32, wn = (w & 1) * (N / 2);
  const int nl = lane & 15, q = lane >> 4;

  floatx4 acc[2][NT];
#pragma unroll
  for (int mt = 0; mt < 2; mt++)
#pragma unroll
    for (int j = 0; j < NT; j++) acc[mt][j] = {0.0f, 0.0f, 0.0f, 0.0f};

#pragma unroll
  for (int K0 = 0; K0 < 4; K0++) {
    bf16x8 ah[2], al[2];
#pragma unroll
    for (int mt = 0; mt < 2; mt++) {
      const int m = wm + mt * 16 + nl;
      const int off = m * 128 + (((K0 * 4 + q) ^ (m & 15)) << 3);
      ah[mt] = *(bf16x8*)(AB + off);
      al[mt] = *(bf16x8*)(AB + 8192 + off);
    }
#pragma unroll
    for (int j = 0; j < NT; j++) {
      const int n = wn + j * 16 + nl;
      const size_t o = (size_t)(K0 * 4 + q) * N * 8 + n * 8;
      const bf16x8 wh = *(const bf16x8*)(WF + o);
      const bf16x8 wl = *(const bf16x8*)(WF + (size_t)N * 128 + o);
#pragma unroll
      for (int mt = 0; mt < 2; mt++) {
        acc[mt][j] = __builtin_amdgcn_mfma_f32_16x16x32_bf16(al[mt], wh, acc[mt][j], 0, 0, 0);
        acc[mt][j] = __builtin_amdgcn_mfma_f32_16x16x32_bf16(ah[mt], wl, acc[mt][j], 0, 0, 0);
        acc[mt][j] = __builtin_amdgcn_mfma_f32_16x16x32_bf16(ah[mt], wh, acc[mt][j], 0, 0, 0);
      }
    }
  }

  // C/D: col=lane&15 (n), row=q*4+r (m)
#pragma unroll
  for (int j = 0; j < NT; j++) {
    const int gc = wn + j * 16 + nl;
    const float bv = bias[gc];
#pragma unroll
    for (int mt = 0; mt < 2; mt++)
#pragma unroll
      for (int r = 0; r < 4; r++) {
        const int m = ml0 + wm + mt * 16 + q * 4 + r;
        const float v = acc[mt][j][r] + bv;
        if (OUT_MODE == 0)
          out[(((size_t)b * NHEAD + (gc >> 4)) * LTOT + m) * DHD + (gc & 15)] = v;
        else
          out[((size_t)b * LTOT + m) * NQA + gc] = v;
      }
  }
}

__global__ __launch_bounds__(256, 4) void gemm_vq(const float* __restrict__ nbr,
                                                  const float* __restrict__ ext,
                                                  const unsigned short* __restrict__ wf_val,
                                                  const unsigned short* __restrict__ wf_qa,
                                                  const float* __restrict__ b_val,
                                                  const float* __restrict__ bias_qa,
                                                  float* __restrict__ value,
                                                  float* __restrict__ qa) {
  __shared__ char smem[32768];
  if (blockIdx.y == 0)
    gemm_wide<128, 0>(nbr, wf_val, b_val, value, blockIdx.z, blockIdx.x * 64, threadIdx.x, smem);
  else
    gemm_wide<192, 1>(ext, wf_qa, bias_qa, qa, blockIdx.z, blockIdx.x * 64, threadIdx.x, smem);
}

// Fused sampler + out-projection. Block = 64 l x one b, 512 thr (8 waves).
// Phase 1 (p-serial, quad-coop): thread = (unit=(l,h), d4); owns all 8 points,
// zero cross-lane shuffles; 4 d4-lanes consume each 64 B pixel line. Sampled
// head-chunk written as bf16 into LDS A-fragment layout (swizzled).
// Phase 2: out-GEMM (2-term bf16 split) from LDS frag + prepped wf_out, bchw store.
__global__ __launch_bounds__(512, 2) void samp_out(const float* __restrict__ value,
                                                   const float* __restrict__ qa,
                                                   const unsigned short* __restrict__ wf_out,
                                                   const float* __restrict__ b_out,
                                                   float* __restrict__ out) {
  __shared__ char smem[33280];  // phase1: frag 16384 B; phase2 epilogue: 128*65*4 B
  unsigned short* FR = (unsigned short*)smem;
  const int t = threadIdx.x;
  const int b = blockIdx.y;
  const int ml0 = blockIdx.x * 64;
  const int d4 = t & 3;
  const int u = t >> 2;  // 0..127

  // ---- phase 1: sample ----
#pragma unroll
  for (int ps = 0; ps < 4; ps++) {
    const int idx = ps * 128 + u;
    const int ll = idx >> 3;  // l within tile
    const int h = idx & 7;
    const int l = ml0 + ll;
    const size_t bl = (size_t)b * LTOT + l;
    const float* qrow = qa + bl * NQA;

    float4 of[4];
#pragma unroll
    for (int j = 0; j < 4; j++) of[j] = *(const float4*)(qrow + h * 16 + j * 4);
    const float4 lga = *(const float4*)(qrow + 128 + h * 8);
    const float4 lgb = *(const float4*)(qrow + 128 + h * 8 + 4);
    float lg[8] = {lga.x, lga.y, lga.z, lga.w, lgb.x, lgb.y, lgb.z, lgb.w};

    float m = lg[0];
#pragma unroll
    for (int p = 1; p < 8; p++) m = fmaxf(m, lg[p]);
    float e[8], s = 0.0f;
#pragma unroll
    for (int p = 0; p < 8; p++) { e[p] = __expf(lg[p] - m); s += e[p]; }
    const float inv = 1.0f / s;

    const float xf = (float)(l & (WS - 1));
    const float yf = (float)(l >> 6);
    const float* vb = value + ((size_t)b * NHEAD + h) * (LTOT * DHD) + d4 * 4;

    float4 o = {0.0f, 0.0f, 0.0f, 0.0f};
#pragma unroll
    for (int p = 0; p < 8; p++) {
      const float ox = (p & 1) ? of[p >> 1].z : of[p >> 1].x;
      const float oy = (p & 1) ? of[p >> 1].w : of[p >> 1].y;
      const float aw = e[p] * inv;
      const float px = xf + 10.0f * fast_tanh(ox);
      const float py = yf + 10.0f * fast_tanh(oy);
      const float x0f = floorf(px), y0f = floorf(py);
      const float fx = px - x0f, fy = py - y0f;
      const int ix = (int)x0f, iy = (int)y0f;
#pragma unroll
      for (int c = 0; c < 4; c++) {
        const int cdx = c & 1, cdy = c >> 1;
        const int jx = ix + cdx, jy = iy + cdy;
        const float wx = cdx ? fx : 1.0f - fx;
        const float wy = cdy ? fy : 1.0f - fy;
        const bool valid = ((unsigned)jx < WS) & ((unsigned)jy < HS);
        const float wc = valid ? aw * wx * wy : 0.0f;
        const int cx = min(max(jx, 0), WS - 1);
        const int cy = min(max(jy, 0), HS - 1);
        const float4 v = *(const float4*)(vb + (size_t)((cy << 6) + cx) * DHD);
        o.x += wc * v.x;
        o.y += wc * v.y;
        o.z += wc * v.z;
        o.w += wc * v.w;
      }
    }

    // frag element (m=ll, k=h*16+d4*4..+3), swizzled layout
    const int off = ll * 128 + (((h * 2 + (d4 >> 1)) ^ (ll & 15)) << 3) + (d4 & 1) * 4;
    ushort4 st = {f2bf_rne(o.x), f2bf_rne(o.y), f2bf_rne(o.z), f2bf_rne(o.w)};
    *(ushort4*)(FR + off) = st;
  }
  __syncthreads();

  // ---- phase 2: out GEMM (64 m x 128 n), 8 waves: wave = 16 m x 64 n ----
  const int w = t >> 6, lane = t & 63;
  const int nl = lane & 15, q = lane >> 4;
  const int wm = (w >> 1) * 16;
  const int wn = (w & 1) * 64;

  floatx4 acc[4];
#pragma unroll
  for (int j = 0; j < 4; j++) acc[j] = {0.0f, 0.0f, 0.0f, 0.0f};

#pragma unroll
  for (int K0 = 0; K0 < 4; K0++) {
    const int m = wm + nl;
    const int off = m * 128 + (((K0 * 4 + q) ^ (m & 15)) << 3);
    const bf16x8 ah = *(bf16x8*)(FR + off);
#pragma unroll
    for (int j = 0; j < 4; j++) {
      const int n = wn + j * 16 + nl;
      const size_t o = (size_t)(K0 * 4 + q) * CM * 8 + n * 8;
      const bf16x8 wh = *(const bf16x8*)(wf_out + o);
      const bf16x8 wl = *(const bf16x8*)(wf_out + (size_t)CM * 128 + o);
      acc[j] = __builtin_amdgcn_mfma_f32_16x16x32_bf16(ah, wl, acc[j], 0, 0, 0);
      acc[j] = __builtin_amdgcn_mfma_f32_16x16x32_bf16(ah, wh, acc[j], 0, 0, 0);
    }
  }

  __syncthreads();  // done reading FR; reuse LDS for transpose
  float* LF = (float*)smem;  // [128 n][65]
#pragma unroll
  for (int j = 0; j < 4; j++) {
    const int n = wn + j * 16 + nl;
#pragma unroll
    for (int r = 0; r < 4; r++) LF[n * 65 + wm + q * 4 + r] = acc[j][r];
  }
  __syncthreads();

#pragma unroll
  for (int i = 0; i < 16; i++) {
    const int idx = t + i * 512;
    const int n = idx >> 6, m = idx & 63;
    out[((size_t)b * CM + n) * LTOT + ml0 + m] = LF[n * 65 + m] + b_out[n];
  }
}

extern "C" void kernel_launch(void* const* d_in, const int* in_sizes, int n_in,
                              void* d_out, int out_size, void* d_ws, size_t ws_size,
                              hipStream_t stream) {
  const float* nbr    = (const float*)d_in[0];
  const float* ext    = (const float*)d_in[1];
  const float* W_val  = (const float*)d_in[2];
  const float* b_val  = (const float*)d_in[3];
  const float* W_off  = (const float*)d_in[4];
  const float* b_off  = (const float*)d_in[5];
  const float* W_attn = (const float*)d_in[6];
  const float* b_attn = (const float*)d_in[7];
  const float* W_out  = (const float*)d_in[8];
  const float* b_out  = (const float*)d_in[9];
  float* out = (float*)d_out;

  float* value = (float*)d_ws;                               // 16.78 MB [b][h][l][16]
  float* qa    = value + (size_t)HB * NHEAD * LTOT * DHD;    // 25.17 MB [b][l][192]
  unsigned short* wf_val = (unsigned short*)(qa + (size_t)HB * LTOT * NQA);  // 64 KB
  unsigned short* wf_qa  = wf_val + 128 * 128 * 2;           // 96 KB
  unsigned short* wf_out = wf_qa + 192 * 128 * 2;            // 64 KB
  float* bias_qa = (float*)(wf_out + 128 * 128 * 2);         // 768 B

  prep<<<56, 256, 0, stream>>>(W_val, W_off, W_attn, W_out, b_off, b_attn,
                               wf_val, wf_qa, wf_out, bias_qa);
  gemm_vq<<<dim3(64, 2, HB), 256, 0, stream>>>(nbr, ext, wf_val, wf_qa, b_val, bias_qa, value, qa);
  samp_out<<<dim3(64, HB), 512, 0, stream>>>(value, qa, wf_out, b_out, out);
}

// Round 8
// 136.141 us; speedup vs baseline: 1.1614x; 1.1614x over previous
//
#include <hip/hip_runtime.h>
#include <cstdint>

#define HB 8
#define CM 128
#define NHEAD 8
#define NPT 8
#define DHD 16
#define HS 64
#define WS 64
#define LTOT 4096
#define NQA 192   // fused off(128) + attn(64)

typedef float floatx4 __attribute__((ext_vector_type(4)));
typedef short bf16x8 __attribute__((ext_vector_type(8)));

__device__ __forceinline__ unsigned short f2bf_rne(float x) {
  unsigned u = __float_as_uint(x);
  return (unsigned short)((u + 0x7FFFu + ((u >> 16) & 1)) >> 16);
}
// truncation split: x ~= hi + lo
__device__ __forceinline__ void split_bf(float x, unsigned short& h, unsigned short& l) {
  unsigned u = __float_as_uint(x);
  h = (unsigned short)(u >> 16);
  float r = x - __uint_as_float(u & 0xFFFF0000u);
  l = (unsigned short)(__float_as_uint(r) >> 16);
}
__device__ __forceinline__ float fast_tanh(float x) {
  float e = __expf(2.0f * x);
  return 1.0f - 2.0f / (e + 1.0f);
}

// Weight prep: bf16 hi/lo fragment layout, element (n,k) at (k>>3)*Nn*8 + n*8 + (k&7).
__global__ __launch_bounds__(256) void prep(const float* __restrict__ Wv,
                                            const float* __restrict__ Wo,
                                            const float* __restrict__ Wa,
                                            const float* __restrict__ Ww,
                                            const float* __restrict__ bo,
                                            const float* __restrict__ ba,
                                            unsigned short* __restrict__ wf_val,
                                            unsigned short* __restrict__ wf_qa,
                                            unsigned short* __restrict__ wf_out,
                                            float* __restrict__ bias_qa) {
  const int gid = blockIdx.x * 256 + threadIdx.x;  // 14336 = 32 k4 * 448 n
  const int k4 = gid / 448;
  const int ng = gid - k4 * 448;

  const float* src;
  unsigned short* dst;
  int Nsrc, Nn, nd, n;
  if (ng < 128) {        src = Wv; dst = wf_val; Nsrc = 128; Nn = 128; n = ng;        nd = n; }
  else if (ng < 256) {   src = Wo; dst = wf_qa;  Nsrc = 128; Nn = 192; n = ng - 128;  nd = n; }
  else if (ng < 320) {   src = Wa; dst = wf_qa;  Nsrc = 64;  Nn = 192; n = ng - 256;  nd = n + 128; }
  else {                 src = Ww; dst = wf_out; Nsrc = 128; Nn = 128; n = ng - 320;  nd = n; }

  ushort4 hi, lo;
  split_bf(src[(k4 * 4 + 0) * Nsrc + n], hi.x, lo.x);
  split_bf(src[(k4 * 4 + 1) * Nsrc + n], hi.y, lo.y);
  split_bf(src[(k4 * 4 + 2) * Nsrc + n], hi.z, lo.z);
  split_bf(src[(k4 * 4 + 3) * Nsrc + n], hi.w, lo.w);
  const int off = (k4 >> 1) * Nn * 8 + nd * 8 + (k4 & 1) * 4;
  *(ushort4*)(dst + off) = hi;
  *(ushort4*)(dst + Nn * 128 + off) = lo;

  if (gid < 128) bias_qa[gid] = bo[gid];
  else if (gid < 192) bias_qa[gid] = ba[gid - 128];
}

// Full-width MFMA GEMM body: tile 64 m x N n per block, A staged ONCE.
// 4 waves; wave tile = 32 m x N/2 n. 3-term bf16 split, K=128.
// OUT 0: value layout, stored BF16: ((b*8 + n/16)*LTOT + m)*16 + n%16
// OUT 1: row-major fp32 [b][l][NQA]
template <int N, int OUT_MODE>
__device__ __forceinline__ void gemm_wide(const float* __restrict__ A,
                                          const unsigned short* __restrict__ WF,
                                          const float* __restrict__ bias,
                                          void* __restrict__ outv,
                                          int b, int ml0, int t, char* smem) {
  constexpr int NT = N / 32;                   // 16-wide n-tiles per wave
  unsigned short* AB = (unsigned short*)smem;  // hi [64][128]; lo at +8192

  // stage A (fp32 k-major [b][128][LTOT]) -> bf16 hi/lo, swizzled
  {
    const float* src = A + (size_t)b * CM * LTOT + ml0;
    const int x = t & 63, kq = t >> 6;
#pragma unroll
    for (int i = 0; i < 8; i++) {
      const int kb = kq * 4 + i * 16;
      ushort4 hi, lo;
      split_bf(src[(size_t)(kb + 0) * LTOT + x], hi.x, lo.x);
      split_bf(src[(size_t)(kb + 1) * LTOT + x], hi.y, lo.y);
      split_bf(src[(size_t)(kb + 2) * LTOT + x], hi.z, lo.z);
      split_bf(src[(size_t)(kb + 3) * LTOT + x], hi.w, lo.w);
      const int off = x * 128 + (((kb >> 3) ^ (x & 15)) << 3) + (kb & 7);
      *(ushort4*)(AB + off) = hi;
      *(ushort4*)(AB + 8192 + off) = lo;
    }
  }
  __syncthreads();

  const int w = t >> 6, lane = t & 63;
  const int wm = (w >> 1) * 32, wn = (w & 1) * (N / 2);
  const int nl = lane & 15, q = lane >> 4;

  floatx4 acc[2][NT];
#pragma unroll
  for (int mt = 0; mt < 2; mt++)
#pragma unroll
    for (int j = 0; j < NT; j++) acc[mt][j] = {0.0f, 0.0f, 0.0f, 0.0f};

#pragma unroll
  for (int K0 = 0; K0 < 4; K0++) {
    bf16x8 ah[2], al[2];
#pragma unroll
    for (int mt = 0; mt < 2; mt++) {
      const int m = wm + mt * 16 + nl;
      const int off = m * 128 + (((K0 * 4 + q) ^ (m & 15)) << 3);
      ah[mt] = *(bf16x8*)(AB + off);
      al[mt] = *(bf16x8*)(AB + 8192 + off);
    }
#pragma unroll
    for (int j = 0; j < NT; j++) {
      const int n = wn + j * 16 + nl;
      const size_t o = (size_t)(K0 * 4 + q) * N * 8 + n * 8;
      const bf16x8 wh = *(const bf16x8*)(WF + o);
      const bf16x8 wl = *(const bf16x8*)(WF + (size_t)N * 128 + o);
#pragma unroll
      for (int mt = 0; mt < 2; mt++) {
        acc[mt][j] = __builtin_amdgcn_mfma_f32_16x16x32_bf16(al[mt], wh, acc[mt][j], 0, 0, 0);
        acc[mt][j] = __builtin_amdgcn_mfma_f32_16x16x32_bf16(ah[mt], wl, acc[mt][j], 0, 0, 0);
        acc[mt][j] = __builtin_amdgcn_mfma_f32_16x16x32_bf16(ah[mt], wh, acc[mt][j], 0, 0, 0);
      }
    }
  }

  // C/D: col=lane&15 (n), row=q*4+r (m)
#pragma unroll
  for (int j = 0; j < NT; j++) {
    const int gc = wn + j * 16 + nl;
    const float bv = bias[gc];
#pragma unroll
    for (int mt = 0; mt < 2; mt++)
#pragma unroll
      for (int r = 0; r < 4; r++) {
        const int m = ml0 + wm + mt * 16 + q * 4 + r;
        const float v = acc[mt][j][r] + bv;
        if (OUT_MODE == 0)
          ((unsigned short*)outv)[(((size_t)b * NHEAD + (gc >> 4)) * LTOT + m) * DHD + (gc & 15)] =
              f2bf_rne(v);
        else
          ((float*)outv)[((size_t)b * LTOT + m) * NQA + gc] = v;
      }
  }
}

__global__ __launch_bounds__(256, 4) void gemm_vq(const float* __restrict__ nbr,
                                                  const float* __restrict__ ext,
                                                  const unsigned short* __restrict__ wf_val,
                                                  const unsigned short* __restrict__ wf_qa,
                                                  const float* __restrict__ b_val,
                                                  const float* __restrict__ bias_qa,
                                                  unsigned short* __restrict__ value,
                                                  float* __restrict__ qa) {
  __shared__ char smem[32768];
  if (blockIdx.y == 0)
    gemm_wide<128, 0>(nbr, wf_val, b_val, value, blockIdx.z, blockIdx.x * 64, threadIdx.x, smem);
  else
    gemm_wide<192, 1>(ext, wf_qa, bias_qa, qa, blockIdx.z, blockIdx.x * 64, threadIdx.x, smem);
}

// Fused sampler + out-projection. 1D grid of 512 blocks; b = blockIdx.x & 7
// (XCD-affinity: each XCD works one batch -> value slice 1.05 MB, L2-resident).
// Phase 0 (setup): thread = (ll,h); computes px/py/aw ONCE per (l,h,p) -> LDS.
// Phase 1 (gather): thread = ((ll,h), d4); pure bilinear from bf16 value.
// Phase 2: out-GEMM from LDS bf16 A-frag + prepped wf_out, bchw store.
__global__ __launch_bounds__(512, 2) void samp_out(const unsigned short* __restrict__ value,
                                                   const float* __restrict__ qa,
                                                   const unsigned short* __restrict__ wf_out,
                                                   const float* __restrict__ b_out,
                                                   float* __restrict__ out) {
  __shared__ char smem[65536];
  float2* WXY = (float2*)smem;                            // [8 p][512 uu], 32768 B
  float* WA = (float*)(smem + 32768);                     // [8 p][512 uu], 16384 B
  unsigned short* FR = (unsigned short*)(smem + 49152);   // bf16 A-frag, 16384 B
  const int t = threadIdx.x;
  const int b = blockIdx.x & 7;
  const int tile = blockIdx.x >> 3;
  const int ml0 = tile * 64;

  // ---- phase 0: per-(l,h) sampling params, no replication ----
  {
    const int ll = t >> 3, h = t & 7;
    const int l = ml0 + ll;
    const float* qrow = qa + ((size_t)b * LTOT + l) * NQA;
    float4 of[4];
#pragma unroll
    for (int j = 0; j < 4; j++) of[j] = *(const float4*)(qrow + h * 16 + j * 4);
    const float4 lga = *(const float4*)(qrow + 128 + h * 8);
    const float4 lgb = *(const float4*)(qrow + 128 + h * 8 + 4);
    const float lg[8] = {lga.x, lga.y, lga.z, lga.w, lgb.x, lgb.y, lgb.z, lgb.w};
    float m = lg[0];
#pragma unroll
    for (int p = 1; p < 8; p++) m = fmaxf(m, lg[p]);
    float e[8], s = 0.0f;
#pragma unroll
    for (int p = 0; p < 8; p++) { e[p] = __expf(lg[p] - m); s += e[p]; }
    const float inv = 1.0f / s;
    const float xf = (float)(l & (WS - 1));
    const float yf = (float)(l >> 6);
#pragma unroll
    for (int p = 0; p < 8; p++) {
      const float ox = (p & 1) ? of[p >> 1].z : of[p >> 1].x;
      const float oy = (p & 1) ? of[p >> 1].w : of[p >> 1].y;
      WXY[p * 512 + t] = {xf + 10.0f * fast_tanh(ox), yf + 10.0f * fast_tanh(oy)};
      WA[p * 512 + t] = e[p] * inv;
    }
  }
  __syncthreads();

  // ---- phase 1: gather ----
  const int d4 = t & 3;
  const int u = t >> 2;  // 0..127
#pragma unroll
  for (int ps = 0; ps < 4; ps++) {
    const int uu = ps * 128 + u;
    const int ll = uu >> 3;
    const int h = uu & 7;
    const unsigned short* vbb = value + ((size_t)(b * NHEAD + h) * LTOT) * DHD + d4 * 4;

    float4 o = {0.0f, 0.0f, 0.0f, 0.0f};
#pragma unroll
    for (int p = 0; p < 8; p++) {
      const float2 pxy = WXY[p * 512 + uu];
      const float aw = WA[p * 512 + uu];
      const float x0f = floorf(pxy.x), y0f = floorf(pxy.y);
      const float fx = pxy.x - x0f, fy = pxy.y - y0f;
      const int ix = (int)x0f, iy = (int)y0f;
#pragma unroll
      for (int c = 0; c < 4; c++) {
        const int cdx = c & 1, cdy = c >> 1;
        const int jx = ix + cdx, jy = iy + cdy;
        const float wx = cdx ? fx : 1.0f - fx;
        const float wy = cdy ? fy : 1.0f - fy;
        const bool valid = ((unsigned)jx < WS) & ((unsigned)jy < HS);
        const float wc = valid ? aw * wx * wy : 0.0f;
        const int cx = min(max(jx, 0), WS - 1);
        const int cy = min(max(jy, 0), HS - 1);
        const uint2 rw = *(const uint2*)(vbb + (size_t)((cy << 6) + cx) * DHD);
        o.x += wc * __uint_as_float(rw.x << 16);
        o.y += wc * __uint_as_float(rw.x & 0xFFFF0000u);
        o.z += wc * __uint_as_float(rw.y << 16);
        o.w += wc * __uint_as_float(rw.y & 0xFFFF0000u);
      }
    }

    // frag element (m=ll, k=h*16+d4*4..+3), swizzled: same scheme as phase 2 reads
    const int off = ll * 128 + (((h * 2 + (d4 >> 1)) ^ (ll & 15)) << 3) + (d4 & 1) * 4;
    ushort4 st = {f2bf_rne(o.x), f2bf_rne(o.y), f2bf_rne(o.z), f2bf_rne(o.w)};
    *(ushort4*)(FR + off) = st;
  }
  __syncthreads();

  // ---- phase 2: out GEMM (64 m x 128 n), 8 waves: wave = 16 m x 64 n ----
  const int w = t >> 6, lane = t & 63;
  const int nl = lane & 15, q = lane >> 4;
  const int wm = (w >> 1) * 16;
  const int wn = (w & 1) * 64;

  floatx4 acc[4];
#pragma unroll
  for (int j = 0; j < 4; j++) acc[j] = {0.0f, 0.0f, 0.0f, 0.0f};

#pragma unroll
  for (int K0 = 0; K0 < 4; K0++) {
    const int m = wm + nl;
    const int off = m * 128 + (((K0 * 4 + q) ^ (m & 15)) << 3);
    const bf16x8 ah = *(bf16x8*)(FR + off);
#pragma unroll
    for (int j = 0; j < 4; j++) {
      const int n = wn + j * 16 + nl;
      const size_t o = (size_t)(K0 * 4 + q) * CM * 8 + n * 8;
      const bf16x8 wh = *(const bf16x8*)(wf_out + o);
      const bf16x8 wl = *(const bf16x8*)(wf_out + (size_t)CM * 128 + o);
      acc[j] = __builtin_amdgcn_mfma_f32_16x16x32_bf16(ah, wl, acc[j], 0, 0, 0);
      acc[j] = __builtin_amdgcn_mfma_f32_16x16x32_bf16(ah, wh, acc[j], 0, 0, 0);
    }
  }

  __syncthreads();  // done reading WXY/WA; FR untouched by LF (LF ends at 33280 < 49152)
  float* LF = (float*)smem;  // [128 n][65]
#pragma unroll
  for (int j = 0; j < 4; j++) {
    const int n = wn + j * 16 + nl;
#pragma unroll
    for (int r = 0; r < 4; r++) LF[n * 65 + wm + q * 4 + r] = acc[j][r];
  }
  __syncthreads();

#pragma unroll
  for (int i = 0; i < 16; i++) {
    const int idx = t + i * 512;
    const int n = idx >> 6, m = idx & 63;
    out[((size_t)b * CM + n) * LTOT + ml0 + m] = LF[n * 65 + m] + b_out[n];
  }
}

extern "C" void kernel_launch(void* const* d_in, const int* in_sizes, int n_in,
                              void* d_out, int out_size, void* d_ws, size_t ws_size,
                              hipStream_t stream) {
  const float* nbr    = (const float*)d_in[0];
  const float* ext    = (const float*)d_in[1];
  const float* W_val  = (const float*)d_in[2];
  const float* b_val  = (const float*)d_in[3];
  const float* W_off  = (const float*)d_in[4];
  const float* b_off  = (const float*)d_in[5];
  const float* W_attn = (const float*)d_in[6];
  const float* b_attn = (const float*)d_in[7];
  const float* W_out  = (const float*)d_in[8];
  const float* b_out  = (const float*)d_in[9];
  float* out = (float*)d_out;

  unsigned short* value = (unsigned short*)d_ws;             // 8.39 MB bf16 [b][h][l][16]
  float* qa = (float*)(value + (size_t)HB * NHEAD * LTOT * DHD);  // 25.17 MB [b][l][192]
  unsigned short* wf_val = (unsigned short*)(qa + (size_t)HB * LTOT * NQA);  // 64 KB
  unsigned short* wf_qa  = wf_val + 128 * 128 * 2;           // 96 KB
  unsigned short* wf_out = wf_qa + 192 * 128 * 2;            // 64 KB
  float* bias_qa = (float*)(wf_out + 128 * 128 * 2);         // 768 B

  prep<<<56, 256, 0, stream>>>(W_val, W_off, W_attn, W_out, b_off, b_attn,
                               wf_val, wf_qa, wf_out, bias_qa);
  gemm_vq<<<dim3(64, 2, HB), 256, 0, stream>>>(nbr, ext, wf_val, wf_qa, b_val, bias_qa, value, qa);
  samp_out<<<dim3(512), 512, 0, stream>>>(value, qa, wf_out, b_out, out);
}